// Round 4
// baseline (173.953 us; speedup 1.0000x reference)
//
#include <hip/hip_runtime.h>
#include <math.h>

#define N_ATOMS 10000
#define N_EDGES 320000
#define C 32
#define NB 8
#define NCOMB 11
#define ED_STRIDE 12   // floats per edge record: u(3) rbf(8) j(1)

// ---- ws layout (byte offsets) ----
#define WS_COUNTS   0u
#define WS_OFFSETS  40064u
#define WS_CURSOR   80128u
#define WS_EDATA    120192u
#define WS_X1T      15480192u     // [N,3,C] floats
#define WS_X2T      19320192u     // [N,9,C] floats
#define WS_TIER2    15480192u
#define WS_TIER1    30840192u

// -------- kernel 1: fused histogram + x1/x2 transpose (output-coalesced) ----
__global__ __launch_bounds__(256) void aux_kernel(
    const float* __restrict__ x1, const float* __restrict__ x2,
    const int* __restrict__ idx_i, float* __restrict__ x1t,
    float* __restrict__ x2t, int* __restrict__ counts)
{
    int t = blockIdx.x * blockDim.x + threadIdx.x;
    if (t < N_EDGES) atomicAdd(&counts[idx_i[t]], 1);

    const int NX1 = N_ATOMS * 3 * C;      // 960000
    const int NX2 = N_ATOMS * 9 * C;      // 2880000
    if (t < NX1) {
        int a = t / (3 * C);
        int r = t - a * (3 * C);
        int m = r >> 5, c = r & 31;
        x1t[t] = x1[(a * C + c) * 3 + m];
    } else {
        int o = t - NX1;
        if (o < NX2) {
            int a = o / (9 * C);
            int r = o - a * (9 * C);
            int m = r >> 5, c = r & 31;
            x2t[o] = x2[(a * C + c) * 9 + m];
        }
    }
}

// -------- kernel 2: single-block exclusive scan (1024 thr); cursor = copy ----
__global__ __launch_bounds__(1024) void scan_kernel(
    const int* __restrict__ counts, int* __restrict__ offsets,
    int* __restrict__ cursor)
{
    __shared__ int part[1024];
    const int PER = 10;                   // 1024*10 >= 10000
    int t = threadIdx.x;
    int base = t * PER;
    int s = 0;
    #pragma unroll
    for (int k = 0; k < PER; ++k) {
        int idx = base + k;
        s += (idx < N_ATOMS) ? counts[idx] : 0;
    }
    part[t] = s;
    __syncthreads();
    for (int off = 1; off < 1024; off <<= 1) {
        int v = (t >= off) ? part[t - off] : 0;
        __syncthreads();
        part[t] += v;
        __syncthreads();
    }
    int run = (t == 0) ? 0 : part[t - 1];
    #pragma unroll
    for (int k = 0; k < PER; ++k) {
        int idx = base + k;
        if (idx < N_ATOMS) { offsets[idx] = run; cursor[idx] = run; run += counts[idx]; }
    }
    if (t == 1023) offsets[N_ATOMS] = part[1023];
}

// -------- kernel 3: per-edge precompute (sincos + Chebyshev), CSR scatter ----
__global__ __launch_bounds__(256) void prep_scatter_kernel(
    const float* __restrict__ pos, const int* __restrict__ idx_i,
    const int* __restrict__ idx_j, int* __restrict__ cursor,
    float* __restrict__ edata)
{
    int e = blockIdx.x * blockDim.x + threadIdx.x;
    if (e >= N_EDGES) return;
    int i = idx_i[e], j = idx_j[e];

    float rx = pos[3*j+0] - pos[3*i+0];
    float ry = pos[3*j+1] - pos[3*i+1];
    float rz = pos[3*j+2] - pos[3*i+2];
    float d  = sqrtf(rx*rx + ry*ry + rz*rz + 1e-12f);
    float invd = 1.0f / d;
    float ux = rx*invd, uy = ry*invd, uz = rz*invd;

    const float PI = 3.14159265358979323846f;
    const float RC = 5.0f;
    float fc    = 0.5f * (cosf(PI * fminf(d, RC) / RC) + 1.0f);
    float pref  = sqrtf(2.0f / RC) * invd * fc;
    float phase = PI * d / RC;

    float s1, c1;
    sincosf(phase, &s1, &c1);
    float twoc = 2.0f * c1;
    float rbf[NB];
    float sp = 0.0f, sc = s1;             // sin(0), sin(phase)
    #pragma unroll
    for (int nb = 0; nb < NB; ++nb) {
        rbf[nb] = pref * sc;
        float sn = twoc * sc - sp;        // sin((n+1)*phase)
        sp = sc; sc = sn;
    }

    int slot = atomicAdd(&cursor[i], 1);
    float4* dst = (float4*)(edata + (size_t)slot * ED_STRIDE);
    dst[0] = make_float4(ux, uy, uz, rbf[0]);
    dst[1] = make_float4(rbf[1], rbf[2], rbf[3], rbf[4]);
    dst[2] = make_float4(rbf[5], rbf[6], rbf[7], __int_as_float(j));
}

// -------- kernel 4: gather — one wave per atom ----------------
// TRANS=1: x1p=[N,3,C], x2p=[N,9,C] (coalesced).  TRANS=0: original layouts.
template<int TRANS>
__global__ __launch_bounds__(256, 2) void gather_kernel(
    const float* __restrict__ x0, const float* __restrict__ x1p,
    const float* __restrict__ x2p, const float* __restrict__ W,
    const float* __restrict__ b, const int* __restrict__ offsets,
    const float* __restrict__ edata, float* __restrict__ out)
{
    int wave = (blockIdx.x * blockDim.x + threadIdx.x) >> 6;
    int lane = threadIdx.x & 63;
    int c = lane & 31;     // channel
    int h = lane >> 5;     // edge-half
    if (wave >= N_ATOMS) return;
    int a = wave;

    // hoist W column c (pre-scaled by 1/NORM) into registers and PIN them
    float Wc[NCOMB][NB], bc[NCOMB];
    #pragma unroll
    for (int k = 0; k < NCOMB; ++k) {
        bc[k] = b[k*C + c] * (1.0f / 32.0f);
        #pragma unroll
        for (int nb = 0; nb < NB; ++nb)
            Wc[k][nb] = W[(k*NB + nb)*C + c] * (1.0f / 32.0f);
    }
    #pragma unroll
    for (int k = 0; k < NCOMB; ++k) {
        asm volatile("" : "+v"(bc[k]));
        #pragma unroll
        for (int nb = 0; nb < NB; ++nb)
            asm volatile("" : "+v"(Wc[k][nb]));
    }

    float acc[13];
    #pragma unroll
    for (int q = 0; q < 13; ++q) acc[q] = 0.0f;

    int start = offsets[a], end = offsets[a + 1];

#define EDGE_BODY(P)                                                          \
    {                                                                         \
        const float4* ed = (const float4*)(edata + (size_t)(P) * ED_STRIDE);  \
        float4 Av = ed[0], Bv = ed[1], Cv = ed[2];                            \
        float ux = Av.x, uy = Av.y, uz = Av.z;                                \
        float rbf[NB] = {Av.w, Bv.x, Bv.y, Bv.z, Bv.w, Cv.x, Cv.y, Cv.z};     \
        int j = __float_as_int(Cv.w);                                         \
        float fn[NCOMB];                                                      \
        _Pragma("unroll")                                                     \
        for (int k = 0; k < NCOMB; ++k) {                                     \
            float t = bc[k];                                                  \
            _Pragma("unroll")                                                 \
            for (int nb = 0; nb < NB; ++nb)                                   \
                t = fmaf(rbf[nb], Wc[k][nb], t);                              \
            fn[k] = t;                                                        \
        }                                                                     \
        float v0 = x0[j*C + c];                                               \
        float v1[3], v2[9];                                                   \
        if (TRANS) {                                                          \
            _Pragma("unroll")                                                 \
            for (int m = 0; m < 3; ++m) v1[m] = x1p[(j*3 + m)*C + c];         \
            _Pragma("unroll")                                                 \
            for (int m = 0; m < 9; ++m) v2[m] = x2p[(j*9 + m)*C + c];         \
        } else {                                                              \
            _Pragma("unroll")                                                 \
            for (int m = 0; m < 3; ++m) v1[m] = x1p[(j*C + c)*3 + m];         \
            _Pragma("unroll")                                                 \
            for (int m = 0; m < 9; ++m) v2[m] = x2p[(j*C + c)*9 + m];         \
        }                                                                     \
        float u[3] = {ux, uy, uz};                                            \
        float t2[3];                                                          \
        _Pragma("unroll")                                                     \
        for (int q = 0; q < 3; ++q)                                           \
            t2[q] = v2[q*3+0]*ux + v2[q*3+1]*uy + v2[q*3+2]*uz;               \
        float s1 = v1[0]*ux + v1[1]*uy + v1[2]*uz;                            \
        float s2 = t2[0]*ux + t2[1]*uy + t2[2]*uz;                            \
        acc[0] += fn[0]*v0 + fn[4]*s1 + fn[9]*s2;                             \
        _Pragma("unroll")                                                     \
        for (int m = 0; m < 3; ++m)                                           \
            acc[1+m] += fn[1]*v0*u[m] + fn[3]*v1[m] + fn[6]*s1*u[m]           \
                      + fn[8]*t2[m];                                          \
        _Pragma("unroll")                                                     \
        for (int q = 0; q < 3; ++q) {                                         \
            float ca = fn[2]*v0*u[q] + fn[5]*v1[q] + fn[10]*t2[q];            \
            _Pragma("unroll")                                                 \
            for (int bb = 0; bb < 3; ++bb)                                    \
                acc[4 + q*3 + bb] += ca*u[bb] + fn[7]*v2[q*3 + bb];           \
        }                                                                     \
    }

    int p = start + h;
    for (; p + 2 < end; p += 4) {       // 2 edges in flight per half-lane
        EDGE_BODY(p);
        EDGE_BODY(p + 2);
    }
    if (p < end) EDGE_BODY(p);
#undef EDGE_BODY

    // combine the two edge-halves
    #pragma unroll
    for (int q = 0; q < 13; ++q)
        acc[q] += __shfl_xor(acc[q], 32);

    if (h == 0) {
        float* out0 = out;
        float* out1 = out + N_ATOMS * C;
        float* out2 = out + N_ATOMS * C * 4;
        out0[a*C + c] = acc[0];
        #pragma unroll
        for (int m = 0; m < 3; ++m) out1[(a*C + c)*3 + m] = acc[1+m];
        #pragma unroll
        for (int q = 0; q < 9; ++q) out2[(a*C + c)*9 + q] = acc[4+q];
    }
}

// ---------------- fallback: atomic path ----------------
__global__ __launch_bounds__(256) void edge_atomic_kernel(
    const float* __restrict__ x0, const float* __restrict__ x1,
    const float* __restrict__ x2, const float* __restrict__ pos,
    const float* __restrict__ W, const float* __restrict__ b,
    const int* __restrict__ idx_i, const int* __restrict__ idx_j,
    float* __restrict__ out)
{
    int tid = blockIdx.x * blockDim.x + threadIdx.x;
    int e = tid >> 5;
    int c = tid & 31;
    if (e >= N_EDGES) return;
    int i = idx_i[e], j = idx_j[e];
    float rx = pos[3*j+0] - pos[3*i+0];
    float ry = pos[3*j+1] - pos[3*i+1];
    float rz = pos[3*j+2] - pos[3*i+2];
    float d  = sqrtf(rx*rx + ry*ry + rz*rz + 1e-12f);
    float invd = 1.0f / d;
    float ux = rx*invd, uy = ry*invd, uz = rz*invd;
    const float PI = 3.14159265358979323846f;
    const float RC = 5.0f;
    float fc   = 0.5f * (cosf(PI * fminf(d, RC) / RC) + 1.0f);
    float pref = sqrtf(2.0f / RC) * invd * fc;
    float phase = PI * d / RC;
    float rbf[NB];
    #pragma unroll
    for (int nb = 0; nb < NB; ++nb) rbf[nb] = pref * sinf((float)(nb+1) * phase);
    float fn[NCOMB];
    #pragma unroll
    for (int k = 0; k < NCOMB; ++k) {
        float acc = b[k*C + c];
        #pragma unroll
        for (int nb = 0; nb < NB; ++nb) acc += rbf[nb] * W[(k*NB + nb)*C + c];
        fn[k] = acc * (1.0f / 32.0f);
    }
    float v0 = x0[j*C + c];
    float v1[3], v2[9];
    #pragma unroll
    for (int m = 0; m < 3; ++m) v1[m] = x1[(j*C + c)*3 + m];
    #pragma unroll
    for (int m = 0; m < 9; ++m) v2[m] = x2[(j*C + c)*9 + m];
    float u[3] = {ux, uy, uz};
    float t2[3];
    #pragma unroll
    for (int q = 0; q < 3; ++q)
        t2[q] = v2[q*3+0]*ux + v2[q*3+1]*uy + v2[q*3+2]*uz;
    float s1 = v1[0]*ux + v1[1]*uy + v1[2]*uz;
    float s2 = t2[0]*ux + t2[1]*uy + t2[2]*uz;
    float* out0 = out;
    float* out1 = out + N_ATOMS * C;
    float* out2 = out + N_ATOMS * C * 4;
    atomicAdd(&out0[i*C + c], fn[0]*v0 + fn[4]*s1 + fn[9]*s2);
    #pragma unroll
    for (int m = 0; m < 3; ++m)
        atomicAdd(&out1[(i*C + c)*3 + m],
                  fn[1]*v0*u[m] + fn[3]*v1[m] + fn[6]*s1*u[m] + fn[8]*t2[m]);
    #pragma unroll
    for (int q = 0; q < 3; ++q) {
        float ca = fn[2]*v0*u[q] + fn[5]*v1[q] + fn[10]*t2[q];
        #pragma unroll
        for (int bb = 0; bb < 3; ++bb)
            atomicAdd(&out2[(i*C + c)*9 + q*3 + bb], ca*u[bb] + fn[7]*v2[q*3 + bb]);
    }
}

extern "C" void kernel_launch(void* const* d_in, const int* in_sizes, int n_in,
                              void* d_out, int out_size, void* d_ws, size_t ws_size,
                              hipStream_t stream) {
    const float* x0    = (const float*)d_in[0];
    const float* x1    = (const float*)d_in[1];
    const float* x2    = (const float*)d_in[2];
    const float* pos   = (const float*)d_in[3];
    const float* W     = (const float*)d_in[4];
    const float* b     = (const float*)d_in[5];
    const int*   idx_i = (const int*)d_in[6];
    const int*   idx_j = (const int*)d_in[7];
    float* out = (float*)d_out;

    int eb = 256, eg = (N_EDGES + eb - 1) / eb;
    int waves_per_block = 256 / 64;
    int ggrid = (N_ATOMS + waves_per_block - 1) / waves_per_block;

    if (ws_size >= WS_TIER1) {
        char* ws = (char*)d_ws;
        int*   counts  = (int*)(ws + WS_COUNTS);
        int*   offsets = (int*)(ws + WS_OFFSETS);
        int*   cursor  = (int*)(ws + WS_CURSOR);
        float* edata   = (float*)(ws + WS_EDATA);
        float* x1t     = (float*)(ws + WS_X1T);
        float* x2t     = (float*)(ws + WS_X2T);

        hipMemsetAsync(counts, 0, N_ATOMS * sizeof(int), stream);

        int total_aux = N_ATOMS * 12 * C;       // 3840000
        int ag = (total_aux + eb - 1) / eb;
        aux_kernel<<<ag, eb, 0, stream>>>(x1, x2, idx_i, x1t, x2t, counts);
        scan_kernel<<<1, 1024, 0, stream>>>(counts, offsets, cursor);
        prep_scatter_kernel<<<eg, eb, 0, stream>>>(pos, idx_i, idx_j, cursor, edata);
        gather_kernel<1><<<ggrid, 256, 0, stream>>>(x0, x1t, x2t, W, b,
                                                    offsets, edata, out);
    } else if (ws_size >= WS_TIER2) {
        char* ws = (char*)d_ws;
        int*   counts  = (int*)(ws + WS_COUNTS);
        int*   offsets = (int*)(ws + WS_OFFSETS);
        int*   cursor  = (int*)(ws + WS_CURSOR);
        float* edata   = (float*)(ws + WS_EDATA);

        hipMemsetAsync(counts, 0, N_ATOMS * sizeof(int), stream);
        aux_kernel<<<(N_EDGES + eb - 1) / eb, eb, 0, stream>>>(
            x1, x2, idx_i, (float*)(ws + WS_CURSOR), (float*)(ws + WS_CURSOR), counts); // transpose skipped below
        // NOTE: tier2 uses original layouts; redo hist only via aux would clobber.
        // Simpler: recount with a dedicated pass is avoided — aux above only did
        // hist for t<N_EDGES and wrote garbage transposes into cursor region,
        // which scan_kernel overwrites afterwards. Safe because x1t/x2t unused.
        scan_kernel<<<1, 1024, 0, stream>>>(counts, offsets, cursor);
        prep_scatter_kernel<<<eg, eb, 0, stream>>>(pos, idx_i, idx_j, cursor, edata);
        gather_kernel<0><<<ggrid, 256, 0, stream>>>(x0, x1, x2, W, b,
                                                    offsets, edata, out);
    } else {
        hipMemsetAsync(d_out, 0, (size_t)out_size * sizeof(float), stream);
        int total_threads = N_EDGES * 32;
        int grid = (total_threads + 255) / 256;
        edge_atomic_kernel<<<grid, 256, 0, stream>>>(
            x0, x1, x2, pos, W, b, idx_i, idx_j, out);
    }
}

// Round 5
// 171.325 us; speedup vs baseline: 1.0153x; 1.0153x over previous
//
#include <hip/hip_runtime.h>
#include <math.h>

#define N_ATOMS 10000
#define N_EDGES 320000
#define C 32
#define NB 8
#define NCOMB 11
#define ED_STRIDE 12   // floats per edge record

// ---- ws layout (byte offsets) ----
#define WS_COUNTS   0u
#define WS_OFFSETS  40960u
#define WS_CURSOR   81920u
#define WS_WT       122880u                   // 32*108 floats = 13824 B
#define WS_EDATA    139264u                   // 320000*48 = 15360000 B
#define WS_XPACK    15499264u                 // 10000*32*64 = 20480000 B
#define WS_TIER1    35979264u
#define WS_TIER2    15499264u

// v_pk_fma_f32 helpers: d/w/bb are float2 (VGPR pairs); r is a float2 whose
// lo (PK_LO) or hi (PK_HI) element is broadcast to both lanes via op_sel.
#define PK0_LO(d,r,w,bb) asm("v_pk_fma_f32 %0, %1, %2, %3 op_sel:[0,0,0] op_sel_hi:[0,1,1]" : "=v"(d) : "v"(r), "v"(w), "v"(bb))
#define PK0_HI(d,r,w,bb) asm("v_pk_fma_f32 %0, %1, %2, %3 op_sel:[1,0,0] op_sel_hi:[1,1,1]" : "=v"(d) : "v"(r), "v"(w), "v"(bb))
#define PK_LO(d,r,w)     asm("v_pk_fma_f32 %0, %1, %2, %0 op_sel:[0,0,0] op_sel_hi:[0,1,1]" : "+v"(d) : "v"(r), "v"(w))
#define PK_HI(d,r,w)     asm("v_pk_fma_f32 %0, %1, %2, %0 op_sel:[1,0,0] op_sel_hi:[1,1,1]" : "+v"(d) : "v"(r), "v"(w))

// -------- kernel 1: histogram + xpack build (one thread per (a,c) == per edge)
__global__ __launch_bounds__(256) void aux_kernel(
    const float* __restrict__ x0, const float* __restrict__ x1,
    const float* __restrict__ x2, const int* __restrict__ idx_i,
    int* __restrict__ counts, float* __restrict__ xpack, int do_pack)
{
    int t = blockIdx.x * blockDim.x + threadIdx.x;
    if (t < N_EDGES) atomicAdd(&counts[idx_i[t]], 1);
    if (do_pack && t < N_ATOMS * C) {
        float v0 = x0[t];
        float a1 = x1[t*3+0], a2 = x1[t*3+1], a3 = x1[t*3+2];
        float b0 = x2[t*9+0], b1 = x2[t*9+1], b2 = x2[t*9+2];
        float b3 = x2[t*9+3], b4 = x2[t*9+4], b5 = x2[t*9+5];
        float b6 = x2[t*9+6], b7 = x2[t*9+7], b8 = x2[t*9+8];
        float* dst = xpack + (size_t)t * 16;
        *(float4*)(dst + 0) = make_float4(v0, a1, a2, a3);
        *(float4*)(dst + 4) = make_float4(b0, b1, b2, b3);
        *(float4*)(dst + 8) = make_float4(b4, b5, b6, b7);
        dst[12] = b8;
    }
}

// -------- kernel 2: exclusive scan (1024 thr) + W repack --------------------
__global__ __launch_bounds__(1024) void scan_kernel(
    const int* __restrict__ counts, int* __restrict__ offsets,
    int* __restrict__ cursor, const float* __restrict__ W,
    const float* __restrict__ b, float* __restrict__ Wt)
{
    // pack Wt: per channel c, 48 float2 W k-pairs [nb][p] + 6 float2 bias pairs
    for (int idx = threadIdx.x; idx < 32*54; idx += 1024) {
        int c = idx / 54, s = idx % 54;
        float2 v;
        if (s < 48) {
            int nb = s / 6, p = s % 6, k0 = 2*p, k1 = 2*p + 1;
            v.x = W[(k0*NB + nb)*C + c] * (1.0f/32.0f);
            v.y = (k1 < NCOMB) ? W[(k1*NB + nb)*C + c] * (1.0f/32.0f) : 0.0f;
        } else {
            int p = s - 48, k0 = 2*p, k1 = 2*p + 1;
            v.x = b[k0*C + c] * (1.0f/32.0f);
            v.y = (k1 < NCOMB) ? b[k1*C + c] * (1.0f/32.0f) : 0.0f;
        }
        ((float2*)Wt)[c*54 + s] = v;
    }

    __shared__ int part[1024];
    const int PER = 10;
    int t = threadIdx.x;
    int base = t * PER;
    int s = 0;
    #pragma unroll
    for (int k = 0; k < PER; ++k) {
        int idx = base + k;
        s += (idx < N_ATOMS) ? counts[idx] : 0;
    }
    part[t] = s;
    __syncthreads();
    for (int off = 1; off < 1024; off <<= 1) {
        int v = (t >= off) ? part[t - off] : 0;
        __syncthreads();
        part[t] += v;
        __syncthreads();
    }
    int run = (t == 0) ? 0 : part[t - 1];
    #pragma unroll
    for (int k = 0; k < PER; ++k) {
        int idx = base + k;
        if (idx < N_ATOMS) { offsets[idx] = run; cursor[idx] = run; run += counts[idx]; }
    }
    if (t == 1023) offsets[N_ATOMS] = part[1023];
}

// -------- kernel 3: per-edge precompute (sincos + Chebyshev), CSR scatter ---
__global__ __launch_bounds__(256) void prep_scatter_kernel(
    const float* __restrict__ pos, const int* __restrict__ idx_i,
    const int* __restrict__ idx_j, int* __restrict__ cursor,
    float* __restrict__ edata)
{
    int e = blockIdx.x * blockDim.x + threadIdx.x;
    if (e >= N_EDGES) return;
    int i = idx_i[e], j = idx_j[e];

    float rx = pos[3*j+0] - pos[3*i+0];
    float ry = pos[3*j+1] - pos[3*i+1];
    float rz = pos[3*j+2] - pos[3*i+2];
    float d  = sqrtf(rx*rx + ry*ry + rz*rz + 1e-12f);
    float invd = 1.0f / d;
    float ux = rx*invd, uy = ry*invd, uz = rz*invd;

    const float PI = 3.14159265358979323846f;
    const float RC = 5.0f;
    float fc    = 0.5f * (cosf(PI * fminf(d, RC) / RC) + 1.0f);
    float pref  = sqrtf(2.0f / RC) * invd * fc;
    float phase = PI * d / RC;

    float s1, c1;
    sincosf(phase, &s1, &c1);
    float twoc = 2.0f * c1;
    float rbf[NB];
    float sp = 0.0f, sc = s1;
    #pragma unroll
    for (int nb = 0; nb < NB; ++nb) {
        rbf[nb] = pref * sc;
        float sn = twoc * sc - sp;
        sp = sc; sc = sn;
    }

    int slot = atomicAdd(&cursor[i], 1);
    float4* dst = (float4*)(edata + (size_t)slot * ED_STRIDE);
    dst[0] = make_float4(ux, uy, uz, rbf[0]);
    dst[1] = make_float4(rbf[1], rbf[2], rbf[3], rbf[4]);
    dst[2] = make_float4(rbf[5], rbf[6], rbf[7], __int_as_float(j));
}

// -------- kernel 4: gather — one wave per atom, pk_fma MLP, packed loads ----
__global__ __launch_bounds__(256, 2) void gather_kernel(
    const float* __restrict__ Wt, const int* __restrict__ offsets,
    const float* __restrict__ edata, const float* __restrict__ xpack,
    float* __restrict__ out)
{
    int wave = (blockIdx.x * blockDim.x + threadIdx.x) >> 6;
    int lane = threadIdx.x & 63;
    int c = lane & 31;
    int h = lane >> 5;
    if (wave >= N_ATOMS) return;
    int a = wave;

    const float2* wrow = (const float2*)Wt + c*54;
    float2 Wp[8][6], bp[6];
    #pragma unroll
    for (int nb = 0; nb < 8; ++nb)
        #pragma unroll
        for (int p = 0; p < 6; ++p) Wp[nb][p] = wrow[nb*6 + p];
    #pragma unroll
    for (int p = 0; p < 6; ++p) bp[p] = wrow[48 + p];
    #pragma unroll
    for (int nb = 0; nb < 8; ++nb)
        #pragma unroll
        for (int p = 0; p < 6; ++p) asm volatile("" : "+v"(Wp[nb][p]));
    #pragma unroll
    for (int p = 0; p < 6; ++p) asm volatile("" : "+v"(bp[p]));

    float acc[13];
    #pragma unroll
    for (int q = 0; q < 13; ++q) acc[q] = 0.0f;

    int start = offsets[a], end = offsets[a + 1];

#define EDGE_BODY(P)                                                          \
    {                                                                         \
        const float2* ed = (const float2*)(edata + (size_t)(P) * ED_STRIDE);  \
        float2 e0 = ed[0], e1 = ed[1], e2 = ed[2];                            \
        float2 e3 = ed[3], e4 = ed[4], e5 = ed[5];                            \
        int j = __float_as_int(e5.y);                                         \
        const float* xb = xpack + ((size_t)(j*C + c) << 4);                   \
        float4 X0 = *(const float4*)xb;                                       \
        float4 X1 = *(const float4*)(xb + 4);                                 \
        float4 X2 = *(const float4*)(xb + 8);                                 \
        float x8 = xb[12];                                                    \
        float2 fnp[6];                                                        \
        _Pragma("unroll") for (int p = 0; p < 6; ++p)                         \
            PK0_HI(fnp[p], e1, Wp[0][p], bp[p]);      /* rbf0 = e1.hi */      \
        _Pragma("unroll") for (int p = 0; p < 6; ++p)                         \
            PK_LO(fnp[p], e2, Wp[1][p]);              /* rbf1 = e2.lo */      \
        _Pragma("unroll") for (int p = 0; p < 6; ++p)                         \
            PK_HI(fnp[p], e2, Wp[2][p]);              /* rbf2 = e2.hi */      \
        _Pragma("unroll") for (int p = 0; p < 6; ++p)                         \
            PK_LO(fnp[p], e3, Wp[3][p]);                                      \
        _Pragma("unroll") for (int p = 0; p < 6; ++p)                         \
            PK_HI(fnp[p], e3, Wp[4][p]);                                      \
        _Pragma("unroll") for (int p = 0; p < 6; ++p)                         \
            PK_LO(fnp[p], e4, Wp[5][p]);                                      \
        _Pragma("unroll") for (int p = 0; p < 6; ++p)                         \
            PK_HI(fnp[p], e4, Wp[6][p]);                                      \
        _Pragma("unroll") for (int p = 0; p < 6; ++p)                         \
            PK_LO(fnp[p], e5, Wp[7][p]);              /* rbf7 = e5.lo */      \
        float fn0 = fnp[0].x, fn1 = fnp[0].y, fn2 = fnp[1].x, fn3 = fnp[1].y; \
        float fn4 = fnp[2].x, fn5 = fnp[2].y, fn6 = fnp[3].x, fn7 = fnp[3].y; \
        float fn8 = fnp[4].x, fn9 = fnp[4].y, fn10 = fnp[5].x;                \
        float ux = e0.x, uy = e0.y, uz = e1.x;                                \
        float v0 = X0.x, v1x = X0.y, v1y = X0.z, v1z = X0.w;                  \
        float t2x = X1.x*ux + X1.y*uy + X1.z*uz;                              \
        float t2y = X1.w*ux + X2.x*uy + X2.y*uz;                              \
        float t2z = X2.z*ux + X2.w*uy + x8*uz;                                \
        float s1 = v1x*ux + v1y*uy + v1z*uz;                                  \
        float s2 = t2x*ux + t2y*uy + t2z*uz;                                  \
        acc[0] += fn0*v0 + fn4*s1 + fn9*s2;                                   \
        float al = fn1*v0 + fn6*s1;                                           \
        acc[1] += al*ux + fn3*v1x + fn8*t2x;                                  \
        acc[2] += al*uy + fn3*v1y + fn8*t2y;                                  \
        acc[3] += al*uz + fn3*v1z + fn8*t2z;                                  \
        float be = fn2*v0;                                                    \
        float cax = be*ux + fn5*v1x + fn10*t2x;                               \
        float cay = be*uy + fn5*v1y + fn10*t2y;                               \
        float caz = be*uz + fn5*v1z + fn10*t2z;                               \
        acc[4]  += cax*ux + fn7*X1.x;                                         \
        acc[5]  += cax*uy + fn7*X1.y;                                         \
        acc[6]  += cax*uz + fn7*X1.z;                                         \
        acc[7]  += cay*ux + fn7*X1.w;                                         \
        acc[8]  += cay*uy + fn7*X2.x;                                         \
        acc[9]  += cay*uz + fn7*X2.y;                                         \
        acc[10] += caz*ux + fn7*X2.z;                                         \
        acc[11] += caz*uy + fn7*X2.w;                                         \
        acc[12] += caz*uz + fn7*x8;                                           \
    }

    int p = start + h;
    for (; p + 2 < end; p += 4) {
        EDGE_BODY(p);
        EDGE_BODY(p + 2);
    }
    if (p < end) EDGE_BODY(p);
#undef EDGE_BODY

    #pragma unroll
    for (int q = 0; q < 13; ++q)
        acc[q] += __shfl_xor(acc[q], 32);

    if (h == 0) {
        float* out0 = out;
        float* out1 = out + N_ATOMS * C;
        float* out2 = out + N_ATOMS * C * 4;
        out0[a*C + c] = acc[0];
        #pragma unroll
        for (int m = 0; m < 3; ++m) out1[(a*C + c)*3 + m] = acc[1+m];
        #pragma unroll
        for (int q = 0; q < 9; ++q) out2[(a*C + c)*9 + q] = acc[4+q];
    }
}

// -------- tier2 gather: R2-style scalar path (original layouts, CSR) -------
__global__ __launch_bounds__(256, 2) void gather_fallback(
    const float* __restrict__ x0, const float* __restrict__ x1,
    const float* __restrict__ x2, const float* __restrict__ W,
    const float* __restrict__ b, const int* __restrict__ offsets,
    const float* __restrict__ edata, float* __restrict__ out)
{
    int wave = (blockIdx.x * blockDim.x + threadIdx.x) >> 6;
    int lane = threadIdx.x & 63;
    int c = lane & 31;
    int h = lane >> 5;
    if (wave >= N_ATOMS) return;
    int a = wave;

    float Wc[NCOMB][NB], bc[NCOMB];
    #pragma unroll
    for (int k = 0; k < NCOMB; ++k) {
        bc[k] = b[k*C + c] * (1.0f / 32.0f);
        #pragma unroll
        for (int nb = 0; nb < NB; ++nb)
            Wc[k][nb] = W[(k*NB + nb)*C + c] * (1.0f / 32.0f);
    }
    #pragma unroll
    for (int k = 0; k < NCOMB; ++k) {
        asm volatile("" : "+v"(bc[k]));
        #pragma unroll
        for (int nb = 0; nb < NB; ++nb) asm volatile("" : "+v"(Wc[k][nb]));
    }

    float acc[13];
    #pragma unroll
    for (int q = 0; q < 13; ++q) acc[q] = 0.0f;

    int start = offsets[a], end = offsets[a + 1];
    for (int p = start + h; p < end; p += 2) {
        const float4* ed = (const float4*)(edata + (size_t)p * ED_STRIDE);
        float4 Av = ed[0], Bv = ed[1], Cv = ed[2];
        float ux = Av.x, uy = Av.y, uz = Av.z;
        float rbf[NB] = {Av.w, Bv.x, Bv.y, Bv.z, Bv.w, Cv.x, Cv.y, Cv.z};
        int j = __float_as_int(Cv.w);
        float fn[NCOMB];
        #pragma unroll
        for (int k = 0; k < NCOMB; ++k) {
            float t = bc[k];
            #pragma unroll
            for (int nb = 0; nb < NB; ++nb) t = fmaf(rbf[nb], Wc[k][nb], t);
            fn[k] = t;
        }
        float v0 = x0[j*C + c];
        float v1[3], v2[9];
        #pragma unroll
        for (int m = 0; m < 3; ++m) v1[m] = x1[(j*C + c)*3 + m];
        #pragma unroll
        for (int m = 0; m < 9; ++m) v2[m] = x2[(j*C + c)*9 + m];
        float u[3] = {ux, uy, uz};
        float t2[3];
        #pragma unroll
        for (int q = 0; q < 3; ++q)
            t2[q] = v2[q*3+0]*ux + v2[q*3+1]*uy + v2[q*3+2]*uz;
        float s1 = v1[0]*ux + v1[1]*uy + v1[2]*uz;
        float s2 = t2[0]*ux + t2[1]*uy + t2[2]*uz;
        acc[0] += fn[0]*v0 + fn[4]*s1 + fn[9]*s2;
        #pragma unroll
        for (int m = 0; m < 3; ++m)
            acc[1+m] += fn[1]*v0*u[m] + fn[3]*v1[m] + fn[6]*s1*u[m] + fn[8]*t2[m];
        #pragma unroll
        for (int q = 0; q < 3; ++q) {
            float ca = fn[2]*v0*u[q] + fn[5]*v1[q] + fn[10]*t2[q];
            #pragma unroll
            for (int bb = 0; bb < 3; ++bb)
                acc[4 + q*3 + bb] += ca*u[bb] + fn[7]*v2[q*3 + bb];
        }
    }

    #pragma unroll
    for (int q = 0; q < 13; ++q)
        acc[q] += __shfl_xor(acc[q], 32);

    if (h == 0) {
        float* out0 = out;
        float* out1 = out + N_ATOMS * C;
        float* out2 = out + N_ATOMS * C * 4;
        out0[a*C + c] = acc[0];
        #pragma unroll
        for (int m = 0; m < 3; ++m) out1[(a*C + c)*3 + m] = acc[1+m];
        #pragma unroll
        for (int q = 0; q < 9; ++q) out2[(a*C + c)*9 + q] = acc[4+q];
    }
}

// ---------------- last-resort atomic path ----------------
__global__ __launch_bounds__(256) void edge_atomic_kernel(
    const float* __restrict__ x0, const float* __restrict__ x1,
    const float* __restrict__ x2, const float* __restrict__ pos,
    const float* __restrict__ W, const float* __restrict__ b,
    const int* __restrict__ idx_i, const int* __restrict__ idx_j,
    float* __restrict__ out)
{
    int tid = blockIdx.x * blockDim.x + threadIdx.x;
    int e = tid >> 5;
    int c = tid & 31;
    if (e >= N_EDGES) return;
    int i = idx_i[e], j = idx_j[e];
    float rx = pos[3*j+0] - pos[3*i+0];
    float ry = pos[3*j+1] - pos[3*i+1];
    float rz = pos[3*j+2] - pos[3*i+2];
    float d  = sqrtf(rx*rx + ry*ry + rz*rz + 1e-12f);
    float invd = 1.0f / d;
    float ux = rx*invd, uy = ry*invd, uz = rz*invd;
    const float PI = 3.14159265358979323846f;
    const float RC = 5.0f;
    float fc   = 0.5f * (cosf(PI * fminf(d, RC) / RC) + 1.0f);
    float pref = sqrtf(2.0f / RC) * invd * fc;
    float phase = PI * d / RC;
    float rbf[NB];
    #pragma unroll
    for (int nb = 0; nb < NB; ++nb) rbf[nb] = pref * sinf((float)(nb+1) * phase);
    float fn[NCOMB];
    #pragma unroll
    for (int k = 0; k < NCOMB; ++k) {
        float acc = b[k*C + c];
        #pragma unroll
        for (int nb = 0; nb < NB; ++nb) acc += rbf[nb] * W[(k*NB + nb)*C + c];
        fn[k] = acc * (1.0f / 32.0f);
    }
    float v0 = x0[j*C + c];
    float v1[3], v2[9];
    #pragma unroll
    for (int m = 0; m < 3; ++m) v1[m] = x1[(j*C + c)*3 + m];
    #pragma unroll
    for (int m = 0; m < 9; ++m) v2[m] = x2[(j*C + c)*9 + m];
    float u[3] = {ux, uy, uz};
    float t2[3];
    #pragma unroll
    for (int q = 0; q < 3; ++q)
        t2[q] = v2[q*3+0]*ux + v2[q*3+1]*uy + v2[q*3+2]*uz;
    float s1 = v1[0]*ux + v1[1]*uy + v1[2]*uz;
    float s2 = t2[0]*ux + t2[1]*uy + t2[2]*uz;
    float* out0 = out;
    float* out1 = out + N_ATOMS * C;
    float* out2 = out + N_ATOMS * C * 4;
    atomicAdd(&out0[i*C + c], fn[0]*v0 + fn[4]*s1 + fn[9]*s2);
    #pragma unroll
    for (int m = 0; m < 3; ++m)
        atomicAdd(&out1[(i*C + c)*3 + m],
                  fn[1]*v0*u[m] + fn[3]*v1[m] + fn[6]*s1*u[m] + fn[8]*t2[m]);
    #pragma unroll
    for (int q = 0; q < 3; ++q) {
        float ca = fn[2]*v0*u[q] + fn[5]*v1[q] + fn[10]*t2[q];
        #pragma unroll
        for (int bb = 0; bb < 3; ++bb)
            atomicAdd(&out2[(i*C + c)*9 + q*3 + bb], ca*u[bb] + fn[7]*v2[q*3 + bb]);
    }
}

extern "C" void kernel_launch(void* const* d_in, const int* in_sizes, int n_in,
                              void* d_out, int out_size, void* d_ws, size_t ws_size,
                              hipStream_t stream) {
    const float* x0    = (const float*)d_in[0];
    const float* x1    = (const float*)d_in[1];
    const float* x2    = (const float*)d_in[2];
    const float* pos   = (const float*)d_in[3];
    const float* W     = (const float*)d_in[4];
    const float* b     = (const float*)d_in[5];
    const int*   idx_i = (const int*)d_in[6];
    const int*   idx_j = (const int*)d_in[7];
    float* out = (float*)d_out;

    int eb = 256, eg = (N_EDGES + eb - 1) / eb;
    int ggrid = (N_ATOMS + 3) / 4;

    if (ws_size >= WS_TIER2) {
        char* ws = (char*)d_ws;
        int*   counts  = (int*)(ws + WS_COUNTS);
        int*   offsets = (int*)(ws + WS_OFFSETS);
        int*   cursor  = (int*)(ws + WS_CURSOR);
        float* Wt      = (float*)(ws + WS_WT);
        float* edata   = (float*)(ws + WS_EDATA);
        float* xpack   = (float*)(ws + WS_XPACK);
        int tier1 = (ws_size >= WS_TIER1);

        hipMemsetAsync(counts, 0, N_ATOMS * sizeof(int), stream);
        aux_kernel<<<eg, eb, 0, stream>>>(x0, x1, x2, idx_i, counts, xpack, tier1);
        scan_kernel<<<1, 1024, 0, stream>>>(counts, offsets, cursor, W, b, Wt);
        prep_scatter_kernel<<<eg, eb, 0, stream>>>(pos, idx_i, idx_j, cursor, edata);
        if (tier1)
            gather_kernel<<<ggrid, 256, 0, stream>>>(Wt, offsets, edata, xpack, out);
        else
            gather_fallback<<<ggrid, 256, 0, stream>>>(x0, x1, x2, W, b,
                                                       offsets, edata, out);
    } else {
        hipMemsetAsync(d_out, 0, (size_t)out_size * sizeof(float), stream);
        int total_threads = N_EDGES * 32;
        int grid = (total_threads + 255) / 256;
        edge_atomic_kernel<<<grid, 256, 0, stream>>>(
            x0, x1, x2, pos, W, b, idx_i, idx_j, out);
    }
}

// Round 6
// 156.656 us; speedup vs baseline: 1.1104x; 1.0936x over previous
//
#include <hip/hip_runtime.h>
#include <hip/hip_fp16.h>
#include <math.h>

#define N_ATOMS 10000
#define N_EDGES 320000
#define C 32
#define NB 8
#define NCOMB 11
#define ED_STRIDE 8    // floats per edge record (32 B)

// ---- ws layout (byte offsets) ----
#define WS_COUNTS   0u
#define WS_OFFSETS  40960u
#define WS_CURSOR   81920u
#define WS_WT       122880u                   // 32*108 floats = 13824 B
#define WS_EDATA    139264u                   // 320000*32 = 10240000 B
#define WS_XPACK    10379264u                 // 320000*32 = 10240000 B (fp16)
#define WS_TIER2    10379264u
#define WS_TIER1    20619264u

__device__ __forceinline__ float2 h2f(unsigned int u) {
    union { unsigned int u; __half2 h; } cv; cv.u = u;
    return __half22float2(cv.h);
}
__device__ __forceinline__ unsigned int f2h(float x, float y) {
    union { unsigned int u; __half2 h; } cv;
    cv.h = __float22half2_rn(make_float2(x, y));
    return cv.u;
}

// v_pk_fma_f32 helpers: d/w/bb are float2 (VGPR pairs); r is a float2 whose
// lo (PK_LO) or hi (PK_HI) element is broadcast to both lanes via op_sel.
#define PK0_LO(d,r,w,bb) asm("v_pk_fma_f32 %0, %1, %2, %3 op_sel:[0,0,0] op_sel_hi:[0,1,1]" : "=v"(d) : "v"(r), "v"(w), "v"(bb))
#define PK0_HI(d,r,w,bb) asm("v_pk_fma_f32 %0, %1, %2, %3 op_sel:[1,0,0] op_sel_hi:[1,1,1]" : "=v"(d) : "v"(r), "v"(w), "v"(bb))
#define PK_LO(d,r,w)     asm("v_pk_fma_f32 %0, %1, %2, %0 op_sel:[0,0,0] op_sel_hi:[0,1,1]" : "+v"(d) : "v"(r), "v"(w))
#define PK_HI(d,r,w)     asm("v_pk_fma_f32 %0, %1, %2, %0 op_sel:[1,0,0] op_sel_hi:[1,1,1]" : "+v"(d) : "v"(r), "v"(w))

// -------- kernel 1: histogram + fp16 xpack build (LDS-staged, coalesced) ----
// grid must be exactly N_ATOMS*C/256 = 1250 blocks; N_EDGES == N_ATOMS*C.
__global__ __launch_bounds__(256) void aux_kernel(
    const float* __restrict__ x0, const float* __restrict__ x1,
    const float* __restrict__ x2, const int* __restrict__ idx_i,
    int* __restrict__ counts, __half* __restrict__ xpack, int do_pack)
{
    int tid = threadIdx.x;
    int a0 = blockIdx.x * 256;            // record base
    int t = a0 + tid;

    atomicAdd(&counts[idx_i[t]], 1);      // t < N_EDGES always (exact grid)

    if (!do_pack) return;

    __shared__ float sx1[768];
    __shared__ float sx2[2304];
    #pragma unroll
    for (int k = 0; k < 3; ++k) sx1[k*256 + tid] = x1[(size_t)a0*3 + k*256 + tid];
    #pragma unroll
    for (int k = 0; k < 9; ++k) sx2[k*256 + tid] = x2[(size_t)a0*9 + k*256 + tid];
    __syncthreads();

    float v0  = x0[t];
    float v1x = sx1[tid*3+0], v1y = sx1[tid*3+1], v1z = sx1[tid*3+2];
    float b0 = sx2[tid*9+0], b1 = sx2[tid*9+1], b2 = sx2[tid*9+2];
    float b3 = sx2[tid*9+3], b4 = sx2[tid*9+4], b5 = sx2[tid*9+5];
    float b6 = sx2[tid*9+6], b7 = sx2[tid*9+7], b8 = sx2[tid*9+8];

    uint4* dst = (uint4*)(xpack + (size_t)t * 16);
    dst[0] = make_uint4(f2h(v0, v1x), f2h(v1y, v1z), f2h(b0, b1), f2h(b2, b3));
    dst[1] = make_uint4(f2h(b4, b5), f2h(b6, b7), f2h(b8, 0.0f), 0u);
}

// -------- kernel 2: exclusive scan (1024 thr) + W repack --------------------
__global__ __launch_bounds__(1024) void scan_kernel(
    const int* __restrict__ counts, int* __restrict__ offsets,
    int* __restrict__ cursor, const float* __restrict__ W,
    const float* __restrict__ b, float* __restrict__ Wt)
{
    for (int idx = threadIdx.x; idx < 32*54; idx += 1024) {
        int c = idx / 54, s = idx % 54;
        float2 v;
        if (s < 48) {
            int nb = s / 6, p = s % 6, k0 = 2*p, k1 = 2*p + 1;
            v.x = W[(k0*NB + nb)*C + c] * (1.0f/32.0f);
            v.y = (k1 < NCOMB) ? W[(k1*NB + nb)*C + c] * (1.0f/32.0f) : 0.0f;
        } else {
            int p = s - 48, k0 = 2*p, k1 = 2*p + 1;
            v.x = b[k0*C + c] * (1.0f/32.0f);
            v.y = (k1 < NCOMB) ? b[k1*C + c] * (1.0f/32.0f) : 0.0f;
        }
        ((float2*)Wt)[c*54 + s] = v;
    }

    __shared__ int part[1024];
    const int PER = 10;
    int t = threadIdx.x;
    int base = t * PER;
    int s = 0;
    #pragma unroll
    for (int k = 0; k < PER; ++k) {
        int idx = base + k;
        s += (idx < N_ATOMS) ? counts[idx] : 0;
    }
    part[t] = s;
    __syncthreads();
    for (int off = 1; off < 1024; off <<= 1) {
        int v = (t >= off) ? part[t - off] : 0;
        __syncthreads();
        part[t] += v;
        __syncthreads();
    }
    int run = (t == 0) ? 0 : part[t - 1];
    #pragma unroll
    for (int k = 0; k < PER; ++k) {
        int idx = base + k;
        if (idx < N_ATOMS) { offsets[idx] = run; cursor[idx] = run; run += counts[idx]; }
    }
    if (t == 1023) offsets[N_ATOMS] = part[1023];
}

// -------- kernel 3: per-edge precompute, CSR scatter (32 B records) ---------
__global__ __launch_bounds__(256) void prep_scatter_kernel(
    const float* __restrict__ pos, const int* __restrict__ idx_i,
    const int* __restrict__ idx_j, int* __restrict__ cursor,
    float* __restrict__ edata)
{
    int e = blockIdx.x * blockDim.x + threadIdx.x;
    if (e >= N_EDGES) return;
    int i = idx_i[e], j = idx_j[e];

    float rx = pos[3*j+0] - pos[3*i+0];
    float ry = pos[3*j+1] - pos[3*i+1];
    float rz = pos[3*j+2] - pos[3*i+2];
    float d  = sqrtf(rx*rx + ry*ry + rz*rz + 1e-12f);
    float invd = 1.0f / d;
    float ux = rx*invd, uy = ry*invd, uz = rz*invd;

    const float PI = 3.14159265358979323846f;
    const float RC = 5.0f;
    float fc    = 0.5f * (cosf(PI * fminf(d, RC) / RC) + 1.0f);
    float pref  = sqrtf(2.0f / RC) * invd * fc;
    float phase = PI * d / RC;

    float s1, c1;
    sincosf(phase, &s1, &c1);
    float twoc = 2.0f * c1;
    float rbf[NB];
    float sp = 0.0f, sc = s1;
    #pragma unroll
    for (int nb = 0; nb < NB; ++nb) {
        rbf[nb] = pref * sc;
        float sn = twoc * sc - sp;
        sp = sc; sc = sn;
    }

    int slot = atomicAdd(&cursor[i], 1);
    float* rec = edata + (size_t)slot * ED_STRIDE;
    *(float4*)rec = make_float4(ux, uy, uz, __int_as_float(j));
    *((uint4*)rec + 1) = make_uint4(f2h(rbf[0], rbf[1]), f2h(rbf[2], rbf[3]),
                                    f2h(rbf[4], rbf[5]), f2h(rbf[6], rbf[7]));
}

// -------- kernel 4: gather — one wave per atom, pk_fma MLP, fp16 loads ------
__global__ __launch_bounds__(256, 2) void gather_kernel(
    const float* __restrict__ Wt, const int* __restrict__ offsets,
    const float* __restrict__ edata, const __half* __restrict__ xpack,
    float* __restrict__ out)
{
    int wave = (blockIdx.x * blockDim.x + threadIdx.x) >> 6;
    int lane = threadIdx.x & 63;
    int c = lane & 31;
    int h = lane >> 5;
    if (wave >= N_ATOMS) return;
    int a = wave;

    const float2* wrow = (const float2*)Wt + c*54;
    float2 Wp[8][6], bp[6];
    #pragma unroll
    for (int nb = 0; nb < 8; ++nb)
        #pragma unroll
        for (int p = 0; p < 6; ++p) Wp[nb][p] = wrow[nb*6 + p];
    #pragma unroll
    for (int p = 0; p < 6; ++p) bp[p] = wrow[48 + p];
    #pragma unroll
    for (int nb = 0; nb < 8; ++nb)
        #pragma unroll
        for (int p = 0; p < 6; ++p) asm volatile("" : "+v"(Wp[nb][p]));
    #pragma unroll
    for (int p = 0; p < 6; ++p) asm volatile("" : "+v"(bp[p]));

    float acc[13];
    #pragma unroll
    for (int q = 0; q < 13; ++q) acc[q] = 0.0f;

    int start = offsets[a], end = offsets[a + 1];

#define EDGE_BODY(P)                                                          \
    {                                                                         \
        const float* rec = edata + (size_t)(P) * ED_STRIDE;                   \
        float4 g0 = *(const float4*)rec;                                      \
        uint4  g1 = *((const uint4*)rec + 1);                                 \
        float2 rp0 = h2f(g1.x), rp1 = h2f(g1.y);                              \
        float2 rp2 = h2f(g1.z), rp3 = h2f(g1.w);                              \
        int j = __float_as_int(g0.w);                                         \
        const uint4* xb = (const uint4*)(xpack + ((size_t)(j*C + c) << 4));   \
        uint4 lo = xb[0], hi = xb[1];                                         \
        float2 X0 = h2f(lo.x), X1 = h2f(lo.y), X2 = h2f(lo.z);                \
        float2 X3 = h2f(lo.w), X4 = h2f(hi.x), X5 = h2f(hi.y), X6 = h2f(hi.z);\
        float2 fnp[6];                                                        \
        _Pragma("unroll") for (int p = 0; p < 6; ++p)                         \
            PK0_LO(fnp[p], rp0, Wp[0][p], bp[p]);                             \
        _Pragma("unroll") for (int p = 0; p < 6; ++p)                         \
            PK_HI(fnp[p], rp0, Wp[1][p]);                                     \
        _Pragma("unroll") for (int p = 0; p < 6; ++p)                         \
            PK_LO(fnp[p], rp1, Wp[2][p]);                                     \
        _Pragma("unroll") for (int p = 0; p < 6; ++p)                         \
            PK_HI(fnp[p], rp1, Wp[3][p]);                                     \
        _Pragma("unroll") for (int p = 0; p < 6; ++p)                         \
            PK_LO(fnp[p], rp2, Wp[4][p]);                                     \
        _Pragma("unroll") for (int p = 0; p < 6; ++p)                         \
            PK_HI(fnp[p], rp2, Wp[5][p]);                                     \
        _Pragma("unroll") for (int p = 0; p < 6; ++p)                         \
            PK_LO(fnp[p], rp3, Wp[6][p]);                                     \
        _Pragma("unroll") for (int p = 0; p < 6; ++p)                         \
            PK_HI(fnp[p], rp3, Wp[7][p]);                                     \
        float fn0 = fnp[0].x, fn1 = fnp[0].y, fn2 = fnp[1].x, fn3 = fnp[1].y; \
        float fn4 = fnp[2].x, fn5 = fnp[2].y, fn6 = fnp[3].x, fn7 = fnp[3].y; \
        float fn8 = fnp[4].x, fn9 = fnp[4].y, fn10 = fnp[5].x;                \
        float ux = g0.x, uy = g0.y, uz = g0.z;                                \
        float v0 = X0.x, v1x = X0.y, v1y = X1.x, v1z = X1.y;                  \
        float c0 = X2.x, c1v = X2.y, c2 = X3.x, c3 = X3.y;                    \
        float c4 = X4.x, c5 = X4.y, c6 = X5.x, c7 = X5.y, c8 = X6.x;          \
        float t2x = c0*ux + c1v*uy + c2*uz;                                   \
        float t2y = c3*ux + c4*uy + c5*uz;                                    \
        float t2z = c6*ux + c7*uy + c8*uz;                                    \
        float s1 = v1x*ux + v1y*uy + v1z*uz;                                  \
        float s2 = t2x*ux + t2y*uy + t2z*uz;                                  \
        acc[0] += fn0*v0 + fn4*s1 + fn9*s2;                                   \
        float al = fn1*v0 + fn6*s1;                                           \
        acc[1] += al*ux + fn3*v1x + fn8*t2x;                                  \
        acc[2] += al*uy + fn3*v1y + fn8*t2y;                                  \
        acc[3] += al*uz + fn3*v1z + fn8*t2z;                                  \
        float be = fn2*v0;                                                    \
        float cax = be*ux + fn5*v1x + fn10*t2x;                               \
        float cay = be*uy + fn5*v1y + fn10*t2y;                               \
        float caz = be*uz + fn5*v1z + fn10*t2z;                               \
        acc[4]  += cax*ux + fn7*c0;                                           \
        acc[5]  += cax*uy + fn7*c1v;                                          \
        acc[6]  += cax*uz + fn7*c2;                                           \
        acc[7]  += cay*ux + fn7*c3;                                           \
        acc[8]  += cay*uy + fn7*c4;                                           \
        acc[9]  += cay*uz + fn7*c5;                                           \
        acc[10] += caz*ux + fn7*c6;                                           \
        acc[11] += caz*uy + fn7*c7;                                           \
        acc[12] += caz*uz + fn7*c8;                                           \
    }

    int p = start + h;
    for (; p + 2 < end; p += 4) {
        EDGE_BODY(p);
        EDGE_BODY(p + 2);
    }
    if (p < end) EDGE_BODY(p);
#undef EDGE_BODY

    #pragma unroll
    for (int q = 0; q < 13; ++q)
        acc[q] += __shfl_xor(acc[q], 32);

    if (h == 0) {
        float* out0 = out;
        float* out1 = out + N_ATOMS * C;
        float* out2 = out + N_ATOMS * C * 4;
        out0[a*C + c] = acc[0];
        #pragma unroll
        for (int m = 0; m < 3; ++m) out1[(a*C + c)*3 + m] = acc[1+m];
        #pragma unroll
        for (int q = 0; q < 9; ++q) out2[(a*C + c)*9 + q] = acc[4+q];
    }
}

// -------- tier2 gather: scalar path, original x layouts, new 32B edata ------
__global__ __launch_bounds__(256, 2) void gather_fallback(
    const float* __restrict__ x0, const float* __restrict__ x1,
    const float* __restrict__ x2, const float* __restrict__ W,
    const float* __restrict__ b, const int* __restrict__ offsets,
    const float* __restrict__ edata, float* __restrict__ out)
{
    int wave = (blockIdx.x * blockDim.x + threadIdx.x) >> 6;
    int lane = threadIdx.x & 63;
    int c = lane & 31;
    int h = lane >> 5;
    if (wave >= N_ATOMS) return;
    int a = wave;

    float Wc[NCOMB][NB], bc[NCOMB];
    #pragma unroll
    for (int k = 0; k < NCOMB; ++k) {
        bc[k] = b[k*C + c] * (1.0f / 32.0f);
        #pragma unroll
        for (int nb = 0; nb < NB; ++nb)
            Wc[k][nb] = W[(k*NB + nb)*C + c] * (1.0f / 32.0f);
    }
    #pragma unroll
    for (int k = 0; k < NCOMB; ++k) {
        asm volatile("" : "+v"(bc[k]));
        #pragma unroll
        for (int nb = 0; nb < NB; ++nb) asm volatile("" : "+v"(Wc[k][nb]));
    }

    float acc[13];
    #pragma unroll
    for (int q = 0; q < 13; ++q) acc[q] = 0.0f;

    int start = offsets[a], end = offsets[a + 1];
    for (int p = start + h; p < end; p += 2) {
        const float* rec = edata + (size_t)p * ED_STRIDE;
        float4 g0 = *(const float4*)rec;
        uint4  g1 = *((const uint4*)rec + 1);
        float2 rp0 = h2f(g1.x), rp1 = h2f(g1.y), rp2 = h2f(g1.z), rp3 = h2f(g1.w);
        float ux = g0.x, uy = g0.y, uz = g0.z;
        float rbf[NB] = {rp0.x, rp0.y, rp1.x, rp1.y, rp2.x, rp2.y, rp3.x, rp3.y};
        int j = __float_as_int(g0.w);
        float fn[NCOMB];
        #pragma unroll
        for (int k = 0; k < NCOMB; ++k) {
            float t = bc[k];
            #pragma unroll
            for (int nb = 0; nb < NB; ++nb) t = fmaf(rbf[nb], Wc[k][nb], t);
            fn[k] = t;
        }
        float v0 = x0[j*C + c];
        float v1[3], v2[9];
        #pragma unroll
        for (int m = 0; m < 3; ++m) v1[m] = x1[(j*C + c)*3 + m];
        #pragma unroll
        for (int m = 0; m < 9; ++m) v2[m] = x2[(j*C + c)*9 + m];
        float u[3] = {ux, uy, uz};
        float t2[3];
        #pragma unroll
        for (int q = 0; q < 3; ++q)
            t2[q] = v2[q*3+0]*ux + v2[q*3+1]*uy + v2[q*3+2]*uz;
        float s1 = v1[0]*ux + v1[1]*uy + v1[2]*uz;
        float s2 = t2[0]*ux + t2[1]*uy + t2[2]*uz;
        acc[0] += fn[0]*v0 + fn[4]*s1 + fn[9]*s2;
        #pragma unroll
        for (int m = 0; m < 3; ++m)
            acc[1+m] += fn[1]*v0*u[m] + fn[3]*v1[m] + fn[6]*s1*u[m] + fn[8]*t2[m];
        #pragma unroll
        for (int q = 0; q < 3; ++q) {
            float ca = fn[2]*v0*u[q] + fn[5]*v1[q] + fn[10]*t2[q];
            #pragma unroll
            for (int bb = 0; bb < 3; ++bb)
                acc[4 + q*3 + bb] += ca*u[bb] + fn[7]*v2[q*3 + bb];
        }
    }

    #pragma unroll
    for (int q = 0; q < 13; ++q)
        acc[q] += __shfl_xor(acc[q], 32);

    if (h == 0) {
        float* out0 = out;
        float* out1 = out + N_ATOMS * C;
        float* out2 = out + N_ATOMS * C * 4;
        out0[a*C + c] = acc[0];
        #pragma unroll
        for (int m = 0; m < 3; ++m) out1[(a*C + c)*3 + m] = acc[1+m];
        #pragma unroll
        for (int q = 0; q < 9; ++q) out2[(a*C + c)*9 + q] = acc[4+q];
    }
}

// ---------------- last-resort atomic path ----------------
__global__ __launch_bounds__(256) void edge_atomic_kernel(
    const float* __restrict__ x0, const float* __restrict__ x1,
    const float* __restrict__ x2, const float* __restrict__ pos,
    const float* __restrict__ W, const float* __restrict__ b,
    const int* __restrict__ idx_i, const int* __restrict__ idx_j,
    float* __restrict__ out)
{
    int tid = blockIdx.x * blockDim.x + threadIdx.x;
    int e = tid >> 5;
    int c = tid & 31;
    if (e >= N_EDGES) return;
    int i = idx_i[e], j = idx_j[e];
    float rx = pos[3*j+0] - pos[3*i+0];
    float ry = pos[3*j+1] - pos[3*i+1];
    float rz = pos[3*j+2] - pos[3*i+2];
    float d  = sqrtf(rx*rx + ry*ry + rz*rz + 1e-12f);
    float invd = 1.0f / d;
    float ux = rx*invd, uy = ry*invd, uz = rz*invd;
    const float PI = 3.14159265358979323846f;
    const float RC = 5.0f;
    float fc   = 0.5f * (cosf(PI * fminf(d, RC) / RC) + 1.0f);
    float pref = sqrtf(2.0f / RC) * invd * fc;
    float phase = PI * d / RC;
    float rbf[NB];
    #pragma unroll
    for (int nb = 0; nb < NB; ++nb) rbf[nb] = pref * sinf((float)(nb+1) * phase);
    float fn[NCOMB];
    #pragma unroll
    for (int k = 0; k < NCOMB; ++k) {
        float acc = b[k*C + c];
        #pragma unroll
        for (int nb = 0; nb < NB; ++nb) acc += rbf[nb] * W[(k*NB + nb)*C + c];
        fn[k] = acc * (1.0f / 32.0f);
    }
    float v0 = x0[j*C + c];
    float v1[3], v2[9];
    #pragma unroll
    for (int m = 0; m < 3; ++m) v1[m] = x1[(j*C + c)*3 + m];
    #pragma unroll
    for (int m = 0; m < 9; ++m) v2[m] = x2[(j*C + c)*9 + m];
    float u[3] = {ux, uy, uz};
    float t2[3];
    #pragma unroll
    for (int q = 0; q < 3; ++q)
        t2[q] = v2[q*3+0]*ux + v2[q*3+1]*uy + v2[q*3+2]*uz;
    float s1 = v1[0]*ux + v1[1]*uy + v1[2]*uz;
    float s2 = t2[0]*ux + t2[1]*uy + t2[2]*uz;
    float* out0 = out;
    float* out1 = out + N_ATOMS * C;
    float* out2 = out + N_ATOMS * C * 4;
    atomicAdd(&out0[i*C + c], fn[0]*v0 + fn[4]*s1 + fn[9]*s2);
    #pragma unroll
    for (int m = 0; m < 3; ++m)
        atomicAdd(&out1[(i*C + c)*3 + m],
                  fn[1]*v0*u[m] + fn[3]*v1[m] + fn[6]*s1*u[m] + fn[8]*t2[m]);
    #pragma unroll
    for (int q = 0; q < 3; ++q) {
        float ca = fn[2]*v0*u[q] + fn[5]*v1[q] + fn[10]*t2[q];
        #pragma unroll
        for (int bb = 0; bb < 3; ++bb)
            atomicAdd(&out2[(i*C + c)*9 + q*3 + bb], ca*u[bb] + fn[7]*v2[q*3 + bb]);
    }
}

extern "C" void kernel_launch(void* const* d_in, const int* in_sizes, int n_in,
                              void* d_out, int out_size, void* d_ws, size_t ws_size,
                              hipStream_t stream) {
    const float* x0    = (const float*)d_in[0];
    const float* x1    = (const float*)d_in[1];
    const float* x2    = (const float*)d_in[2];
    const float* pos   = (const float*)d_in[3];
    const float* W     = (const float*)d_in[4];
    const float* b     = (const float*)d_in[5];
    const int*   idx_i = (const int*)d_in[6];
    const int*   idx_j = (const int*)d_in[7];
    float* out = (float*)d_out;

    int eb = 256, eg = (N_EDGES + eb - 1) / eb;   // 1250, exact
    int ggrid = (N_ATOMS + 3) / 4;

    if (ws_size >= WS_TIER2) {
        char* ws = (char*)d_ws;
        int*    counts  = (int*)(ws + WS_COUNTS);
        int*    offsets = (int*)(ws + WS_OFFSETS);
        int*    cursor  = (int*)(ws + WS_CURSOR);
        float*  Wt      = (float*)(ws + WS_WT);
        float*  edata   = (float*)(ws + WS_EDATA);
        __half* xpack   = (__half*)(ws + WS_XPACK);
        int tier1 = (ws_size >= WS_TIER1);

        hipMemsetAsync(counts, 0, N_ATOMS * sizeof(int), stream);
        aux_kernel<<<eg, eb, 0, stream>>>(x0, x1, x2, idx_i, counts, xpack, tier1);
        scan_kernel<<<1, 1024, 0, stream>>>(counts, offsets, cursor, W, b, Wt);
        prep_scatter_kernel<<<eg, eb, 0, stream>>>(pos, idx_i, idx_j, cursor, edata);
        if (tier1)
            gather_kernel<<<ggrid, 256, 0, stream>>>(Wt, offsets, edata, xpack, out);
        else
            gather_fallback<<<ggrid, 256, 0, stream>>>(x0, x1, x2, W, b,
                                                       offsets, edata, out);
    } else {
        hipMemsetAsync(d_out, 0, (size_t)out_size * sizeof(float), stream);
        int total_threads = N_EDGES * 32;
        int grid = (total_threads + 255) / 256;
        edge_atomic_kernel<<<grid, 256, 0, stream>>>(
            x0, x1, x2, pos, W, b, idx_i, idx_j, out);
    }
}